// Round 4
// baseline (422.745 us; speedup 1.0000x reference)
//
#include <hip/hip_runtime.h>

#define Bz 8
#define Lz 2048
#define Dz 256
#define Nz 64
#define SP 68   // LDS row stride for 64x64 tiles: 16B-aligned rows, bank-spread

__device__ __forceinline__ float softplusf(float x) {
  return (x > 20.f) ? x : log1pf(expf(x));
}

// C = alpha*A*B (+ I if addI). 256 threads. Caller barriers before/after.
__device__ __forceinline__ void matmul64(float* __restrict__ Cb,
                                         const float* __restrict__ Ab,
                                         const float* __restrict__ Bb,
                                         float alpha, bool addI, int tid) {
  const int n = tid & 63, q = tid >> 6;
  float arow[64];
#pragma unroll
  for (int mm = 0; mm < 16; ++mm) {
    const float4 a4 = *(const float4*)(Ab + n * SP + mm * 4);
    arow[4 * mm + 0] = a4.x; arow[4 * mm + 1] = a4.y;
    arow[4 * mm + 2] = a4.z; arow[4 * mm + 3] = a4.w;
  }
  float acc[16];
#pragma unroll
  for (int i = 0; i < 16; ++i) acc[i] = 0.f;
  const float* Bq = Bb + q * 16;
#pragma unroll 8
  for (int m = 0; m < 64; ++m) {
    const float4 b0 = *(const float4*)(Bq + m * SP + 0);
    const float4 b1 = *(const float4*)(Bq + m * SP + 4);
    const float4 b2 = *(const float4*)(Bq + m * SP + 8);
    const float4 b3 = *(const float4*)(Bq + m * SP + 12);
    const float a = arow[m];
    acc[0]  = fmaf(a, b0.x, acc[0]);  acc[1]  = fmaf(a, b0.y, acc[1]);
    acc[2]  = fmaf(a, b0.z, acc[2]);  acc[3]  = fmaf(a, b0.w, acc[3]);
    acc[4]  = fmaf(a, b1.x, acc[4]);  acc[5]  = fmaf(a, b1.y, acc[5]);
    acc[6]  = fmaf(a, b1.z, acc[6]);  acc[7]  = fmaf(a, b1.w, acc[7]);
    acc[8]  = fmaf(a, b2.x, acc[8]);  acc[9]  = fmaf(a, b2.y, acc[9]);
    acc[10] = fmaf(a, b2.z, acc[10]); acc[11] = fmaf(a, b2.w, acc[11]);
    acc[12] = fmaf(a, b3.x, acc[12]); acc[13] = fmaf(a, b3.y, acc[13]);
    acc[14] = fmaf(a, b3.z, acc[14]); acc[15] = fmaf(a, b3.w, acc[15]);
  }
#pragma unroll
  for (int i = 0; i < 16; ++i) {
    const int c = q * 16 + i;
    Cb[n * SP + c] = alpha * acc[i] + ((addI && c == n) ? 1.f : 0.f);
  }
}

// One block per channel d: discretize (expm Taylor + scaling-squaring,
// dB = dt*phi1(A*dt)*Bp_d), then k[d,l] = C^T E^l dB via U/W chunking.
// Writes kT[l*Dz + d].
__global__ __launch_bounds__(256) void s4_build(
    const float* __restrict__ log_A, const float* __restrict__ Bp,
    const float* __restrict__ Cp, const float* __restrict__ log_delta,
    float* __restrict__ kT) {
  __shared__ alignas(16) float MB0[Nz * SP];
  __shared__ alignas(16) float MB1[Nz * SP];
  __shared__ alignas(16) float MB2[Nz * SP];
  __shared__ float vecv[Nz], vecterm[Nz], wvec[Nz];
  __shared__ float pr[4][Nz + 8];
  __shared__ float pr2[4][Nz + 8];
  __shared__ float scal;

  const int tid = threadIdx.x;
  const int d = blockIdx.x;
  const int n = tid & 63, q = tid >> 6;

  const float dt = softplusf(log_delta[d]) + 1e-6f;

  // M = softplus(log_A) * dt
  for (int idx = tid; idx < Nz * Nz; idx += 256) {
    const int r = idx >> 6, c = idx & 63;
    MB0[r * SP + c] = softplusf(log_A[idx]) * dt;
  }
  __syncthreads();

  // inf-norm of M -> scaling exponent s
  {
    float p = 0.f;
#pragma unroll
    for (int m0 = 0; m0 < 16; ++m0) p += fabsf(MB0[n * SP + q * 16 + m0]);
    pr[q][n] = p;
  }
  __syncthreads();
  if (tid < 64) {
    float rs = pr[0][tid] + pr[1][tid] + pr[2][tid] + pr[3][tid];
#pragma unroll
    for (int off = 32; off > 0; off >>= 1) rs = fmaxf(rs, __shfl_xor(rs, off));
    if (tid == 0) scal = rs;
  }
  __syncthreads();
  const float norm = scal;
  int s = 0;
  if (norm > 0.25f) {   // uniform branch
    s = (int)ceilf(log2f(norm * 4.0f));
    const float sc = exp2f((float)(-s));
    for (int idx = tid; idx < Nz * Nz; idx += 256) {
      const int r = idx >> 6, c = idx & 63;
      MB0[r * SP + c] *= sc;   // each element owned by one thread
    }
    __syncthreads();
  }

  // E = expm(M) via Taylor-6 Horner: P = I + M/6; P = I + M*P/k, k=5..1
  for (int idx = tid; idx < Nz * Nz; idx += 256) {
    const int r = idx >> 6, c = idx & 63;
    MB1[r * SP + c] = MB0[r * SP + c] * (1.f / 6.f) + ((r == c) ? 1.f : 0.f);
  }
  __syncthreads();
  float* P = MB1;
  float* T = MB2;
#pragma unroll 1
  for (int k = 5; k >= 1; --k) {
    matmul64(T, MB0, P, 1.f / (float)k, true, tid);
    __syncthreads();
    float* tswap = P; P = T; T = tswap;
  }

  // v = phi1(M)*Bp_d via Taylor matvecs: term_j = M*term_{j-1}/(j+1)
  if (tid < 64) {
    const float bv = Bp[d * Nz + tid];
    vecv[tid] = bv;
    vecterm[tid] = bv;
  }
  __syncthreads();
#pragma unroll 1
  for (int j = 1; j <= 6; ++j) {
    float p = 0.f;
#pragma unroll
    for (int m0 = 0; m0 < 16; ++m0) {
      const int m = q * 16 + m0;
      p += MB0[n * SP + m] * vecterm[m];
    }
    pr[q][n] = p;
    __syncthreads();
    if (tid < 64) {
      const float t = (pr[0][tid] + pr[1][tid] + pr[2][tid] + pr[3][tid]) / (float)(j + 1);
      vecterm[tid] = t;
      vecv[tid] += t;
    }
    __syncthreads();
  }

  // undo scaling: v <- 0.5*(E*v + v); E <- E*E   (s times; s==0 for this input)
  float* E = P;
  float* spare = T;
#pragma unroll 1
  for (int i = 0; i < s; ++i) {
    float p = 0.f;
#pragma unroll
    for (int m0 = 0; m0 < 16; ++m0) {
      const int m = q * 16 + m0;
      p += E[n * SP + m] * vecv[m];
    }
    pr[q][n] = p;
    __syncthreads();
    if (tid < 64)
      vecv[tid] = 0.5f * (pr[0][tid] + pr[1][tid] + pr[2][tid] + pr[3][tid] + vecv[tid]);
    __syncthreads();
    matmul64(spare, E, E, 1.f, false, tid);
    __syncthreads();
    float* tswap = E; E = spare; spare = tswap;
  }

  // U chain: U[:,0] = dt*v = dB; fill U[:, 2^j..2^{j+1}) = E^{2^j} * U[:,0..2^j)
  // interleaved with squarings; M (MB0) is dead -> reuse as U.
  float* const UB = MB0;
  if (tid < 64) UB[tid * SP + 0] = dt * vecv[tid];
  __syncthreads();
#pragma unroll 1
  for (int j = 0; j < 6; ++j) {
    const int c = 1 << j;
    for (int col = q; col < c; col += 4) {
      float p = 0.f;
#pragma unroll 16
      for (int m = 0; m < 64; ++m) p += E[n * SP + m] * UB[m * SP + col];
      UB[n * SP + c + col] = p;   // write cols >= c, read cols < c: disjoint
    }
    __syncthreads();
    matmul64(spare, E, E, 1.f, false, tid);
    __syncthreads();
    float* tswap = E; E = spare; spare = tswap;
  }
  // now E = E^64

  // W loop: w_0 = Cp_d; k[d,64j+r] = w_j . U[:,r]; w_{j+1} = E64^T w_j
  if (tid < 64) wvec[tid] = Cp[d * Nz + tid];
  __syncthreads();
  float* const kTd = kT + d;
#pragma unroll 1
  for (int j = 0; j < 32; ++j) {
    float pd = 0.f, pw = 0.f;
#pragma unroll
    for (int m0 = 0; m0 < 16; ++m0) {
      const int m = q * 16 + m0;
      pd += wvec[m] * UB[m * SP + n];   // dot for r = n
      pw += E[m * SP + n] * wvec[m];    // (E64^T w)[n]
    }
    pr[q][n] = pd;
    pr2[q][n] = pw;
    __syncthreads();
    if (tid < 64) {
      kTd[(size_t)(j * 64 + tid) * Dz] =
          pr[0][tid] + pr[1][tid] + pr[2][tid] + pr[3][tid];
      wvec[tid] = pr2[0][tid] + pr2[1][tid] + pr2[2][tid] + pr2[3][tid];
    }
    __syncthreads();
  }
}

// Balanced split-k causal conv. Block = 256 threads (thread = channel d),
// grid (p<32, b<8, z<nsplit). Block handles output tiles tt=p and 63-p
// (pairing -> uniform 65 total chunk-passes per (p,b) pair), with source
// chunks split across z into SEPARATE partial buffers (no atomics, no
// spill-prone 512-thread blocks). Register-rolled 63-tap k window.
// Partial sums are combined in s4_gemm's staging load.
__global__ __launch_bounds__(256) void s4_conv(
    const float* __restrict__ x, const float* __restrict__ kT,
    float* __restrict__ yw, int nsplit) {
  const int d = threadIdx.x;
  const int p = blockIdx.x;
  const int b = blockIdx.y;
  const int z = blockIdx.z;
  float* const ywz = yw + (size_t)z * ((size_t)Bz * Lz * Dz);
  const float* xb = x + ((size_t)b * Lz) * Dz + d;
  const float* kd = kT + d;

#pragma unroll 1
  for (int tile = 0; tile < 2; ++tile) {
    const int tt = tile ? (63 - p) : p;
    const int t0 = tt * 32;
    const int nch = tt + 1;
    const int beg = (nch * z) / nsplit;
    const int end = (nch * (z + 1)) / nsplit;

    float acc[32];
#pragma unroll
    for (int i = 0; i < 32; ++i) acc[i] = 0.f;

    if (beg < end) {
      int base = t0 - beg * 32;                 // decreases by 32 per chunk
      float kw[63];                             // kw[u] = k[base-31+u]
#pragma unroll
      for (int u = 0; u < 63; ++u) {
        const int idx = base - 31 + u;
        kw[u] = (idx >= 0) ? kd[(size_t)idx * Dz] : 0.f;
      }
      for (int sc = beg;;) {
        const int s0 = sc * 32;
#pragma unroll
        for (int jj = 0; jj < 32; ++jj) {
          const float xv = xb[(size_t)(s0 + jj) * Dz];
#pragma unroll
          for (int i = 0; i < 32; ++i)
            acc[i] = fmaf(kw[i - jj + 31], xv, acc[i]);
        }
        ++sc;
        if (sc >= end) break;
        base -= 32;
        // roll window: shift up 32, load 32 new low taps
#pragma unroll
        for (int u = 62; u >= 32; --u) kw[u] = kw[u - 32];
#pragma unroll
        for (int u = 0; u < 32; ++u) {
          const int idx = base - 31 + u;
          kw[u] = (idx >= 0) ? kd[(size_t)idx * Dz] : 0.f;
        }
      }
    }

    // unconditional write (buffers are poison-filled, not zeroed)
    float* ywp = ywz + ((size_t)b * Lz + t0) * Dz + d;
#pragma unroll
    for (int i = 0; i < 32; ++i)
      ywp[(size_t)i * Dz] = acc[i];
  }
}

// out[r,c] = sum_d (sum_z yw_z[r,d] + x[r,d]*skip[d]) * W[c,d] + b[c]
// LDS-tiled 64x64, 4x4 microtile.
__global__ __launch_bounds__(256) void s4_gemm(
    const float* __restrict__ yw, int nsplit,
    const float* __restrict__ x, const float* __restrict__ skip_D,
    const float* __restrict__ Wo, const float* __restrict__ bo,
    float* __restrict__ out) {
  __shared__ alignas(16) float Ys[64 * 17];
  __shared__ alignas(16) float Ws[64 * 17];
  const int tid = threadIdx.x;
  const int r0 = blockIdx.x * 64;
  const int c0 = blockIdx.y * 64;
  const int tr = tid >> 4, tc = tid & 15;
  const int lr = tid >> 2, lq = tid & 3;
  const size_t YWS = (size_t)Bz * Lz * Dz;
  float acc[16];
#pragma unroll
  for (int i = 0; i < 16; ++i) acc[i] = 0.f;
  for (int kc = 0; kc < 16; ++kc) {
    const int dc0 = kc * 16;
    const size_t yoff = (size_t)(r0 + lr) * Dz + dc0 + lq * 4;
    const float4 xa = *(const float4*)(x + yoff);
    const float4 sk = *(const float4*)(skip_D + dc0 + lq * 4);
    const float4 wa = *(const float4*)(Wo + (size_t)(c0 + lr) * Dz + dc0 + lq * 4);
    float4 ya;
    ya.x = xa.x * sk.x; ya.y = xa.y * sk.y;
    ya.z = xa.z * sk.z; ya.w = xa.w * sk.w;
#pragma unroll 1
    for (int zz = 0; zz < nsplit; ++zz) {
      const float4 t = *(const float4*)(yw + (size_t)zz * YWS + yoff);
      ya.x += t.x; ya.y += t.y; ya.z += t.z; ya.w += t.w;
    }
    Ys[lr * 17 + lq * 4 + 0] = ya.x;
    Ys[lr * 17 + lq * 4 + 1] = ya.y;
    Ys[lr * 17 + lq * 4 + 2] = ya.z;
    Ys[lr * 17 + lq * 4 + 3] = ya.w;
    Ws[lr * 17 + lq * 4 + 0] = wa.x; Ws[lr * 17 + lq * 4 + 1] = wa.y;
    Ws[lr * 17 + lq * 4 + 2] = wa.z; Ws[lr * 17 + lq * 4 + 3] = wa.w;
    __syncthreads();
#pragma unroll
    for (int dk = 0; dk < 16; ++dk) {
      float yv[4], wv[4];
#pragma unroll
      for (int i = 0; i < 4; ++i) yv[i] = Ys[(tr * 4 + i) * 17 + dk];
#pragma unroll
      for (int i = 0; i < 4; ++i) wv[i] = Ws[(tc * 4 + i) * 17 + dk];
#pragma unroll
      for (int i = 0; i < 4; ++i)
#pragma unroll
        for (int jj = 0; jj < 4; ++jj)
          acc[i * 4 + jj] = fmaf(yv[i], wv[jj], acc[i * 4 + jj]);
    }
    __syncthreads();
  }
#pragma unroll
  for (int i = 0; i < 4; ++i)
#pragma unroll
    for (int jj = 0; jj < 4; ++jj) {
      const int cc = c0 + tc * 4 + jj;
      out[(size_t)(r0 + tr * 4 + i) * Dz + cc] = acc[i * 4 + jj] + bo[cc];
    }
}

extern "C" void kernel_launch(void* const* d_in, const int* in_sizes, int n_in,
                              void* d_out, int out_size, void* d_ws, size_t ws_size,
                              hipStream_t stream) {
  const float* x         = (const float*)d_in[0];
  const float* log_A     = (const float*)d_in[1];
  const float* Bp        = (const float*)d_in[2];
  const float* Cp        = (const float*)d_in[3];
  const float* log_delta = (const float*)d_in[4];
  const float* skip_D    = (const float*)d_in[5];
  const float* W_out     = (const float*)d_in[6];
  const float* b_out     = (const float*)d_in[7];
  float* out = (float*)d_out;

  // workspace layout: kT [Lz*Dz] then nsplit partial yw buffers [Bz*Lz*Dz]
  const size_t kT_bytes  = (size_t)Lz * Dz * sizeof(float);
  const size_t buf_bytes = (size_t)Bz * Lz * Dz * sizeof(float);
  int nsplit = 1;
  if (ws_size >= kT_bytes + 4 * buf_bytes) nsplit = 4;
  else if (ws_size >= kT_bytes + 2 * buf_bytes) nsplit = 2;

  float* kT = (float*)d_ws;
  float* yw = kT + (size_t)Lz * Dz;

  hipLaunchKernelGGL(s4_build, dim3(Dz), dim3(256), 0, stream,
                     log_A, Bp, Cp, log_delta, kT);
  hipLaunchKernelGGL(s4_conv, dim3(32, Bz, nsplit), dim3(256), 0, stream,
                     x, kT, yw, nsplit);
  hipLaunchKernelGGL(s4_gemm, dim3((Bz * Lz) / 64, Dz / 64), dim3(256), 0, stream,
                     yw, nsplit, x, skip_D, W_out, b_out, out);
}

// Round 5
// 355.584 us; speedup vs baseline: 1.1889x; 1.1889x over previous
//
#include <hip/hip_runtime.h>

#define Bz 8
#define Lz 2048
#define Dz 256
#define Nz 64
#define SP 68   // LDS row stride for 64x64 tiles: 16B-aligned rows, bank-spread

__device__ __forceinline__ float softplusf(float x) {
  return (x > 20.f) ? x : log1pf(expf(x));
}

// C = alpha*A*B (+ I if addI). 256 threads. Caller barriers before/after.
__device__ __forceinline__ void matmul64(float* __restrict__ Cb,
                                         const float* __restrict__ Ab,
                                         const float* __restrict__ Bb,
                                         float alpha, bool addI, int tid) {
  const int n = tid & 63, q = tid >> 6;
  float arow[64];
#pragma unroll
  for (int mm = 0; mm < 16; ++mm) {
    const float4 a4 = *(const float4*)(Ab + n * SP + mm * 4);
    arow[4 * mm + 0] = a4.x; arow[4 * mm + 1] = a4.y;
    arow[4 * mm + 2] = a4.z; arow[4 * mm + 3] = a4.w;
  }
  float acc[16];
#pragma unroll
  for (int i = 0; i < 16; ++i) acc[i] = 0.f;
  const float* Bq = Bb + q * 16;
#pragma unroll 8
  for (int m = 0; m < 64; ++m) {
    const float4 b0 = *(const float4*)(Bq + m * SP + 0);
    const float4 b1 = *(const float4*)(Bq + m * SP + 4);
    const float4 b2 = *(const float4*)(Bq + m * SP + 8);
    const float4 b3 = *(const float4*)(Bq + m * SP + 12);
    const float a = arow[m];
    acc[0]  = fmaf(a, b0.x, acc[0]);  acc[1]  = fmaf(a, b0.y, acc[1]);
    acc[2]  = fmaf(a, b0.z, acc[2]);  acc[3]  = fmaf(a, b0.w, acc[3]);
    acc[4]  = fmaf(a, b1.x, acc[4]);  acc[5]  = fmaf(a, b1.y, acc[5]);
    acc[6]  = fmaf(a, b1.z, acc[6]);  acc[7]  = fmaf(a, b1.w, acc[7]);
    acc[8]  = fmaf(a, b2.x, acc[8]);  acc[9]  = fmaf(a, b2.y, acc[9]);
    acc[10] = fmaf(a, b2.z, acc[10]); acc[11] = fmaf(a, b2.w, acc[11]);
    acc[12] = fmaf(a, b3.x, acc[12]); acc[13] = fmaf(a, b3.y, acc[13]);
    acc[14] = fmaf(a, b3.z, acc[14]); acc[15] = fmaf(a, b3.w, acc[15]);
  }
#pragma unroll
  for (int i = 0; i < 16; ++i) {
    const int c = q * 16 + i;
    Cb[n * SP + c] = alpha * acc[i] + ((addI && c == n) ? 1.f : 0.f);
  }
}

// Transpose x[b][t][d] -> xT[d][b][t]. 64x64 LDS tiles.
__global__ __launch_bounds__(256) void s4_xt(const float* __restrict__ x,
                                             float* __restrict__ xT) {
  __shared__ float tile[64][65];
  const int t0 = blockIdx.x * 64, d0 = blockIdx.y * 64, b = blockIdx.z;
  const int lt = threadIdx.x & 63, rq = threadIdx.x >> 6;
#pragma unroll
  for (int i = 0; i < 16; ++i) {
    const int row = rq + i * 4;
    tile[row][lt] = x[((size_t)b * Lz + t0 + row) * Dz + d0 + lt];
  }
  __syncthreads();
#pragma unroll
  for (int i = 0; i < 16; ++i) {
    const int row = rq + i * 4;   // row = d index within tile
    xT[((size_t)(d0 + row) * Bz + b) * Lz + t0 + lt] = tile[lt][row];
  }
}

// Per-channel build: discretize (expm Taylor + scaling-squaring,
// dB = dt*phi1(A*dt)*Bp_d), then dual doubling chains:
//   U[:,r] = E^r dB,  V[:,r] = (E^T)^r C,  r in [0,64), E -> E^64.
// Emits (all [d]-major, transposed for coalesced consumption):
//   UUf[d][j][n]  = U[n][63-j]          (inj operand, pre-flipped)
//   E64T[d][m][n] = E64[n][m]
//   WmT[d][m][r]  = W[r][m] = (V[:,r+1])[m]   (r=63 -> E64^T C)
//   kloc[d][tau]  = C^T E^tau dB, tau in [0,64)
__global__ __launch_bounds__(256) void s4_build(
    const float* __restrict__ log_A, const float* __restrict__ Bp,
    const float* __restrict__ Cp, const float* __restrict__ log_delta,
    float* __restrict__ UUf, float* __restrict__ E64T,
    float* __restrict__ WmT, float* __restrict__ kloc) {
  __shared__ alignas(16) float MB0[Nz * SP];
  __shared__ alignas(16) float MB1[Nz * SP];
  __shared__ alignas(16) float MB2[Nz * SP];
  __shared__ alignas(16) float MB3[Nz * SP];
  __shared__ float vecv[Nz], vecterm[Nz], v64s[Nz];
  __shared__ float pr[4][Nz + 8];
  __shared__ float pr2[4][Nz + 8];
  __shared__ float scal;

  const int tid = threadIdx.x;
  const int d = blockIdx.x;
  const int n = tid & 63, q = tid >> 6;

  const float dt = softplusf(log_delta[d]) + 1e-6f;

  // M = softplus(log_A) * dt
  for (int idx = tid; idx < Nz * Nz; idx += 256) {
    const int r = idx >> 6, c = idx & 63;
    MB0[r * SP + c] = softplusf(log_A[idx]) * dt;
  }
  __syncthreads();

  // inf-norm of M -> scaling exponent s
  {
    float p = 0.f;
#pragma unroll
    for (int m0 = 0; m0 < 16; ++m0) p += fabsf(MB0[n * SP + q * 16 + m0]);
    pr[q][n] = p;
  }
  __syncthreads();
  if (tid < 64) {
    float rs = pr[0][tid] + pr[1][tid] + pr[2][tid] + pr[3][tid];
#pragma unroll
    for (int off = 32; off > 0; off >>= 1) rs = fmaxf(rs, __shfl_xor(rs, off));
    if (tid == 0) scal = rs;
  }
  __syncthreads();
  const float norm = scal;
  int s = 0;
  if (norm > 0.25f) {   // uniform branch
    s = (int)ceilf(log2f(norm * 4.0f));
    const float sc = exp2f((float)(-s));
    for (int idx = tid; idx < Nz * Nz; idx += 256) {
      const int r = idx >> 6, c = idx & 63;
      MB0[r * SP + c] *= sc;
    }
    __syncthreads();
  }

  // E = expm(M) via Taylor-6 Horner: P = I + M/6; P = I + M*P/k, k=5..1
  for (int idx = tid; idx < Nz * Nz; idx += 256) {
    const int r = idx >> 6, c = idx & 63;
    MB1[r * SP + c] = MB0[r * SP + c] * (1.f / 6.f) + ((r == c) ? 1.f : 0.f);
  }
  __syncthreads();
  float* P = MB1;
  float* T = MB2;
#pragma unroll 1
  for (int k = 5; k >= 1; --k) {
    matmul64(T, MB0, P, 1.f / (float)k, true, tid);
    __syncthreads();
    float* tswap = P; P = T; T = tswap;
  }

  // v = phi1(M)*Bp_d via Taylor matvecs
  if (tid < 64) {
    const float bv = Bp[d * Nz + tid];
    vecv[tid] = bv;
    vecterm[tid] = bv;
  }
  __syncthreads();
#pragma unroll 1
  for (int j = 1; j <= 6; ++j) {
    float p = 0.f;
#pragma unroll
    for (int m0 = 0; m0 < 16; ++m0) {
      const int m = q * 16 + m0;
      p += MB0[n * SP + m] * vecterm[m];
    }
    pr[q][n] = p;
    __syncthreads();
    if (tid < 64) {
      const float t = (pr[0][tid] + pr[1][tid] + pr[2][tid] + pr[3][tid]) / (float)(j + 1);
      vecterm[tid] = t;
      vecv[tid] += t;
    }
    __syncthreads();
  }

  // undo scaling: v <- 0.5*(E*v + v); E <- E*E  (s==0 for this input)
  float* E = P;
  float* spare = T;
#pragma unroll 1
  for (int i = 0; i < s; ++i) {
    float p = 0.f;
#pragma unroll
    for (int m0 = 0; m0 < 16; ++m0) {
      const int m = q * 16 + m0;
      p += E[n * SP + m] * vecv[m];
    }
    pr[q][n] = p;
    __syncthreads();
    if (tid < 64)
      vecv[tid] = 0.5f * (pr[0][tid] + pr[1][tid] + pr[2][tid] + pr[3][tid] + vecv[tid]);
    __syncthreads();
    matmul64(spare, E, E, 1.f, false, tid);
    __syncthreads();
    float* tswap = E; E = spare; spare = tswap;
  }

  // Dual doubling chains. MB0 = U, MB3 = V. vecterm := dB = dt*vecv.
  float* const UB = MB0;
  float* const VB = MB3;
  if (tid < 64) {
    const float dBv = dt * vecv[tid];
    vecterm[tid] = dBv;
    UB[tid * SP + 0] = dBv;
    VB[tid * SP + 0] = Cp[d * Nz + tid];
  }
  __syncthreads();
#pragma unroll 1
  for (int j = 0; j < 6; ++j) {
    const int c = 1 << j;
    for (int col = q; col < c; col += 4) {
      float pu = 0.f, pv = 0.f;
#pragma unroll 16
      for (int m = 0; m < 64; ++m) {
        pu += E[n * SP + m] * UB[m * SP + col];   // E * U[:,col]
        pv += E[m * SP + n] * VB[m * SP + col];   // E^T * V[:,col]
      }
      UB[n * SP + c + col] = pu;
      VB[n * SP + c + col] = pv;
    }
    __syncthreads();
    matmul64(spare, E, E, 1.f, false, tid);
    __syncthreads();
    float* tswap = E; E = spare; spare = tswap;
  }
  // now E = E^64

  // v64 = E64^T C  and  k[tau] = V[:,tau] . dB  (two reductions in one pass)
  {
    float pa = 0.f, pb = 0.f;
#pragma unroll
    for (int m0 = 0; m0 < 16; ++m0) {
      const int m = q * 16 + m0;
      pa += E[m * SP + n] * VB[m * SP + 0];   // (E64^T C)[n]
      pb += VB[m * SP + n] * vecterm[m];      // k[n]
    }
    pr[q][n] = pa;
    pr2[q][n] = pb;
  }
  __syncthreads();
  if (tid < 64) {
    v64s[tid] = pr[0][tid] + pr[1][tid] + pr[2][tid] + pr[3][tid];
    kloc[(size_t)d * 64 + tid] =
        pr2[0][tid] + pr2[1][tid] + pr2[2][tid] + pr2[3][tid];
  }
  __syncthreads();

  // Emit per-d operand matrices (writes coalesced over low 6 bits)
  for (int idx = tid; idx < 4096; idx += 256) {
    const int hi = idx >> 6, lo = idx & 63;
    UUf[(size_t)d * 4096 + idx]  = UB[lo * SP + (63 - hi)];       // [j][n]
    E64T[(size_t)d * 4096 + idx] = E[lo * SP + hi];               // [m][n]
    WmT[(size_t)d * 4096 + idx]  = (lo < 63) ? VB[hi * SP + lo + 1]
                                             : v64s[hi];          // [m][r]
  }
}

// Chunked state scan, one block per d. state[c+1] = E64*state[c] + Uf*xchunk.
// Writes S[d][c][b][n] = state ENTERING chunk c (S[d][0]=0).
// Thread (n = tid&63, q = tid>>6) handles b = q and b = q+4; E64/Uf rows
// cached in registers, S/X chunk columns broadcast-read from LDS as float4.
__global__ __launch_bounds__(256) void s4_scan(
    const float* __restrict__ xT, const float* __restrict__ UUf,
    const float* __restrict__ E64T, float* __restrict__ S) {
  __shared__ float Xs[8][64];
  __shared__ float Ss[8][64];
  const int d = blockIdx.x;
  const int tid = threadIdx.x, n = tid & 63, q = tid >> 6;
  const float* UU = UUf + (size_t)d * 4096;
  const float* ET = E64T + (size_t)d * 4096;
  float arowU[64], arowE[64];
#pragma unroll
  for (int j = 0; j < 64; ++j) arowU[j] = UU[j * 64 + n];  // U[n][63-j]
#pragma unroll
  for (int m = 0; m < 64; ++m) arowE[m] = ET[m * 64 + n];  // E64[n][m]
  Ss[q][n] = 0.f;
  Ss[q + 4][n] = 0.f;
  __syncthreads();
  const float* xd = xT + (size_t)d * Bz * Lz;
  float* Sd = S + (size_t)d * (32 * 8 * 64);
#pragma unroll 1
  for (int c = 0; c < 32; ++c) {
    Xs[q][n]     = xd[(size_t)q * Lz + c * 64 + n];
    Xs[q + 4][n] = xd[(size_t)(q + 4) * Lz + c * 64 + n];
    Sd[c * 512 + q * 64 + n]       = Ss[q][n];
    Sd[c * 512 + (q + 4) * 64 + n] = Ss[q + 4][n];
    __syncthreads();
    float acc0 = 0.f, acc1 = 0.f;
#pragma unroll
    for (int m = 0; m < 64; m += 4) {
      const float4 s0 = *(const float4*)&Ss[q][m];
      const float4 s1 = *(const float4*)&Ss[q + 4][m];
      const float4 x0 = *(const float4*)&Xs[q][m];
      const float4 x1 = *(const float4*)&Xs[q + 4][m];
      acc0 = fmaf(arowE[m], s0.x, acc0);     acc1 = fmaf(arowE[m], s1.x, acc1);
      acc0 = fmaf(arowE[m + 1], s0.y, acc0); acc1 = fmaf(arowE[m + 1], s1.y, acc1);
      acc0 = fmaf(arowE[m + 2], s0.z, acc0); acc1 = fmaf(arowE[m + 2], s1.z, acc1);
      acc0 = fmaf(arowE[m + 3], s0.w, acc0); acc1 = fmaf(arowE[m + 3], s1.w, acc1);
      acc0 = fmaf(arowU[m], x0.x, acc0);     acc1 = fmaf(arowU[m], x1.x, acc1);
      acc0 = fmaf(arowU[m + 1], x0.y, acc0); acc1 = fmaf(arowU[m + 1], x1.y, acc1);
      acc0 = fmaf(arowU[m + 2], x0.z, acc0); acc1 = fmaf(arowU[m + 2], x1.z, acc1);
      acc0 = fmaf(arowU[m + 3], x0.w, acc0); acc1 = fmaf(arowU[m + 3], x1.w, acc1);
    }
    __syncthreads();
    Ss[q][n] = acc0;
    Ss[q + 4][n] = acc1;
    __syncthreads();
  }
}

// Output: yT[d][b][c*64+r] = sum_m W[r][m] S[d][c][b][m]
//                          + sum_{j<=r} k[r-j] x[d][b][c*64+j]
// One block per d; W rows in registers; 4 (b,c)-columns staged per pass.
__global__ __launch_bounds__(256) void s4_out(
    const float* __restrict__ xT, const float* __restrict__ S,
    const float* __restrict__ WmT, const float* __restrict__ kloc,
    float* __restrict__ yT) {
  __shared__ float kx[128];          // kx[63+tau] = k[tau]; kx[0..62] = 0
  __shared__ float colS[4][64];
  __shared__ float colX[4][64];
  const int d = blockIdx.x;
  const int tid = threadIdx.x, r = tid & 63, q = tid >> 6;
  float arowW[64];
#pragma unroll
  for (int m = 0; m < 64; ++m) arowW[m] = WmT[(size_t)d * 4096 + m * 64 + r];
  if (tid < 63) kx[tid] = 0.f;
  if (tid < 64) kx[63 + tid] = kloc[(size_t)d * 64 + tid];
  __syncthreads();
  const float* xd = xT + (size_t)d * Bz * Lz;
  const float* Sd = S + (size_t)d * (32 * 8 * 64);
  float* yd = yT + (size_t)d * Bz * Lz;
#pragma unroll 1
  for (int p = 0; p < 64; ++p) {
    {
      const int col = p * 4 + q;               // col = c*8 + b
      const int cc = col >> 3, bb = col & 7;
      colS[q][r] = Sd[cc * 512 + bb * 64 + r];
      colX[q][r] = xd[(size_t)bb * Lz + cc * 64 + r];
    }
    __syncthreads();
    const int col = p * 4 + q;
    const int cc = col >> 3, bb = col & 7;
    float acc = 0.f;
#pragma unroll
    for (int m = 0; m < 64; m += 4) {
      const float4 sv = *(const float4*)&colS[q][m];
      acc = fmaf(arowW[m], sv.x, acc);
      acc = fmaf(arowW[m + 1], sv.y, acc);
      acc = fmaf(arowW[m + 2], sv.z, acc);
      acc = fmaf(arowW[m + 3], sv.w, acc);
    }
#pragma unroll
    for (int j = 0; j < 64; j += 4) {
      const float4 xv = *(const float4*)&colX[q][j];
      acc = fmaf(kx[63 + r - j], xv.x, acc);
      acc = fmaf(kx[62 + r - j], xv.y, acc);
      acc = fmaf(kx[61 + r - j], xv.z, acc);
      acc = fmaf(kx[60 + r - j], xv.w, acc);
    }
    yd[(size_t)bb * Lz + cc * 64 + r] = acc;
    __syncthreads();
  }
}

// out[row,c] = sum_d (yT[d][row] + x[row,d]*skip[d]) * W[c,d] + b[c]
// rows = (b,t); LDS-tiled 64x64, 4x4 microtile.
__global__ __launch_bounds__(256) void s4_gemm(
    const float* __restrict__ yT, const float* __restrict__ x,
    const float* __restrict__ skip_D, const float* __restrict__ Wo,
    const float* __restrict__ bo, float* __restrict__ out) {
  __shared__ alignas(16) float Ys[64 * 17];
  __shared__ alignas(16) float Ws[64 * 17];
  const int tid = threadIdx.x;
  const int r0 = blockIdx.x * 64;
  const int c0 = blockIdx.y * 64;
  const int brow = r0 >> 11;           // batch (2048 rows per b)
  const int t0 = r0 & 2047;
  const int tr = tid >> 4, tc = tid & 15;
  const int lr = tid >> 2, lq = tid & 3;
  float acc[16];
#pragma unroll
  for (int i = 0; i < 16; ++i) acc[i] = 0.f;
  for (int kc = 0; kc < 16; ++kc) {
    const int dc0 = kc * 16;
    const float4 xa = *(const float4*)(x + (size_t)(r0 + lr) * Dz + dc0 + lq * 4);
    const float4 sk = *(const float4*)(skip_D + dc0 + lq * 4);
    const float4 wa = *(const float4*)(Wo + (size_t)(c0 + lr) * Dz + dc0 + lq * 4);
    float yv[4];
#pragma unroll
    for (int i = 0; i < 4; ++i) {
      const int dd = dc0 + lq * 4 + i;
      yv[i] = yT[((size_t)dd * Bz + brow) * Lz + t0 + lr];
    }
    Ys[lr * 17 + lq * 4 + 0] = yv[0] + xa.x * sk.x;
    Ys[lr * 17 + lq * 4 + 1] = yv[1] + xa.y * sk.y;
    Ys[lr * 17 + lq * 4 + 2] = yv[2] + xa.z * sk.z;
    Ys[lr * 17 + lq * 4 + 3] = yv[3] + xa.w * sk.w;
    Ws[lr * 17 + lq * 4 + 0] = wa.x; Ws[lr * 17 + lq * 4 + 1] = wa.y;
    Ws[lr * 17 + lq * 4 + 2] = wa.z; Ws[lr * 17 + lq * 4 + 3] = wa.w;
    __syncthreads();
#pragma unroll
    for (int dk = 0; dk < 16; ++dk) {
      float yvv[4], wv[4];
#pragma unroll
      for (int i = 0; i < 4; ++i) yvv[i] = Ys[(tr * 4 + i) * 17 + dk];
#pragma unroll
      for (int i = 0; i < 4; ++i) wv[i] = Ws[(tc * 4 + i) * 17 + dk];
#pragma unroll
      for (int i = 0; i < 4; ++i)
#pragma unroll
        for (int jj = 0; jj < 4; ++jj)
          acc[i * 4 + jj] = fmaf(yvv[i], wv[jj], acc[i * 4 + jj]);
    }
    __syncthreads();
  }
#pragma unroll
  for (int i = 0; i < 4; ++i)
#pragma unroll
    for (int jj = 0; jj < 4; ++jj) {
      const int cc = c0 + tc * 4 + jj;
      out[(size_t)(r0 + tr * 4 + i) * Dz + cc] = acc[i * 4 + jj] + bo[cc];
    }
}

extern "C" void kernel_launch(void* const* d_in, const int* in_sizes, int n_in,
                              void* d_out, int out_size, void* d_ws, size_t ws_size,
                              hipStream_t stream) {
  const float* x         = (const float*)d_in[0];
  const float* log_A     = (const float*)d_in[1];
  const float* Bp        = (const float*)d_in[2];
  const float* Cp        = (const float*)d_in[3];
  const float* log_delta = (const float*)d_in[4];
  const float* skip_D    = (const float*)d_in[5];
  const float* W_out     = (const float*)d_in[6];
  const float* b_out     = (const float*)d_in[7];
  float* out = (float*)d_out;

  // workspace (floats): xT, yT, UUf, E64T, WmT, kloc, S  (~63 MB total)
  float* xT   = (float*)d_ws;                              // D*B*L
  float* yT   = xT + (size_t)Dz * Bz * Lz;                 // D*B*L
  float* UUf  = yT + (size_t)Dz * Bz * Lz;                 // D*64*64
  float* E64T = UUf + (size_t)Dz * 4096;
  float* WmT  = E64T + (size_t)Dz * 4096;
  float* kloc = WmT + (size_t)Dz * 4096;                   // D*64
  float* S    = kloc + (size_t)Dz * 64;                    // D*32*8*64

  hipLaunchKernelGGL(s4_xt, dim3(Lz / 64, Dz / 64, Bz), dim3(256), 0, stream,
                     x, xT);
  hipLaunchKernelGGL(s4_build, dim3(Dz), dim3(256), 0, stream,
                     log_A, Bp, Cp, log_delta, UUf, E64T, WmT, kloc);
  hipLaunchKernelGGL(s4_scan, dim3(Dz), dim3(256), 0, stream,
                     xT, UUf, E64T, S);
  hipLaunchKernelGGL(s4_out, dim3(Dz), dim3(256), 0, stream,
                     xT, S, WmT, kloc, yT);
  hipLaunchKernelGGL(s4_gemm, dim3((Bz * Lz) / 64, Dz / 64), dim3(256), 0, stream,
                     yT, x, skip_D, W_out, b_out, out);
}